// Round 2
// baseline (5747.511 us; speedup 1.0000x reference)
//
#include <hip/hip_runtime.h>
#include <math.h>

// ---------------- tiled fp32 GEMM: C = (A @ B[^T]) * scale (+ bias) --------
// A: [M,K] row-major lda. B: NN -> [K,N] ldb; BT -> [N,K] ldb (dot of rows).
// Tiles: 64x64x16, 256 threads, 4x4 microtile. Exact tiling (no bounds checks):
// all M,N,K here are multiples of 64/64/16.
template<bool BT, bool HAS_BIAS>
__global__ __launch_bounds__(256)
void gemm_k(const float* __restrict__ A, const float* __restrict__ B,
            const float* __restrict__ bias, float* __restrict__ C,
            int K, int lda, int ldb, int ldc,
            long long sA, long long sB, long long sC, float scale)
{
    A += (long long)blockIdx.z * sA;
    B += (long long)blockIdx.z * sB;
    C += (long long)blockIdx.z * sC;
    const int bm = blockIdx.y * 64;
    const int bn = blockIdx.x * 64;
    const int tid = threadIdx.x;

    __shared__ float As[16][68];   // [k][m], +4 pad keeps 16B align, breaks pow2 stride
    __shared__ float Bs[16][68];   // [k][n]

    const int tm = tid & 15, tn = tid >> 4;
    const int m0 = tm * 4, n0 = tn * 4;

    const int la_m = tid >> 2;          // 0..63
    const int la_k = (tid & 3) * 4;     // 0,4,8,12
    const int lb_k = tid >> 4;          // 0..15 (NN)
    const int lb_n = (tid & 15) * 4;    // 0..60 (NN)

    float acc[4][4] = {};

    const int nkt = K >> 4;
    for (int kt = 0; kt < nkt; ++kt) {
        const int k0 = kt << 4;
        float4 av = *(const float4*)&A[(long long)(bm + la_m) * lda + k0 + la_k];
        float4 bv;
        if (BT) bv = *(const float4*)&B[(long long)(bn + la_m) * ldb + k0 + la_k];
        else    bv = *(const float4*)&B[(long long)(k0 + lb_k) * ldb + bn + lb_n];
        __syncthreads();               // protect LDS from previous iter's readers
        As[la_k + 0][la_m] = av.x; As[la_k + 1][la_m] = av.y;
        As[la_k + 2][la_m] = av.z; As[la_k + 3][la_m] = av.w;
        if (BT) {
            Bs[la_k + 0][la_m] = bv.x; Bs[la_k + 1][la_m] = bv.y;
            Bs[la_k + 2][la_m] = bv.z; Bs[la_k + 3][la_m] = bv.w;
        } else {
            *(float4*)&Bs[lb_k][lb_n] = bv;
        }
        __syncthreads();
#pragma unroll
        for (int k = 0; k < 16; ++k) {
            float4 a = *(const float4*)&As[k][m0];
            float4 b = *(const float4*)&Bs[k][n0];
            acc[0][0] = fmaf(a.x, b.x, acc[0][0]); acc[0][1] = fmaf(a.x, b.y, acc[0][1]);
            acc[0][2] = fmaf(a.x, b.z, acc[0][2]); acc[0][3] = fmaf(a.x, b.w, acc[0][3]);
            acc[1][0] = fmaf(a.y, b.x, acc[1][0]); acc[1][1] = fmaf(a.y, b.y, acc[1][1]);
            acc[1][2] = fmaf(a.y, b.z, acc[1][2]); acc[1][3] = fmaf(a.y, b.w, acc[1][3]);
            acc[2][0] = fmaf(a.z, b.x, acc[2][0]); acc[2][1] = fmaf(a.z, b.y, acc[2][1]);
            acc[2][2] = fmaf(a.z, b.z, acc[2][2]); acc[2][3] = fmaf(a.z, b.w, acc[2][3]);
            acc[3][0] = fmaf(a.w, b.x, acc[3][0]); acc[3][1] = fmaf(a.w, b.y, acc[3][1]);
            acc[3][2] = fmaf(a.w, b.z, acc[3][2]); acc[3][3] = fmaf(a.w, b.w, acc[3][3]);
        }
    }

    float4 bb = make_float4(0.f, 0.f, 0.f, 0.f);
    if (HAS_BIAS) bb = *(const float4*)&bias[bn + n0];
#pragma unroll
    for (int i = 0; i < 4; ++i) {
        float4 o;
        o.x = fmaf(acc[i][0], scale, bb.x);
        o.y = fmaf(acc[i][1], scale, bb.y);
        o.z = fmaf(acc[i][2], scale, bb.z);
        o.w = fmaf(acc[i][3], scale, bb.w);
        *(float4*)&C[(long long)(bm + m0 + i) * ldc + bn + n0] = o;
    }
}

// ---------------- gw = softmax(V @ w_gp) over 49 groups, one wave per row ---
// qkv rows are chunk-local; V at column offset 1536, ld 2304.
__global__ __launch_bounds__(64)
void gw_k(const float* __restrict__ qkv, const float* __restrict__ wgp,
          float* __restrict__ gw)
{
    const long long row = blockIdx.x;
    const int lane = threadIdx.x;
    const float* v = qkv + row * 2304 + 1536;
    float acc = 0.f;
    if (lane < 49) {
        for (int d = 0; d < 768; ++d)
            acc = fmaf(v[d], wgp[d * 49 + lane], acc);
    }
    float logit = (lane < 49) ? acc : -INFINITY;
    float m = logit;
    for (int off = 32; off; off >>= 1)
        m = fmaxf(m, __shfl_xor(m, off, 64));
    float e = (lane < 49) ? expf(logit - m) : 0.f;
    float s = e;
    for (int off = 32; off; off >>= 1)
        s += __shfl_xor(s, off, 64);
    if (lane < 49) gw[row * 49 + lane] = e / s;
}

// ---------------- fused softmax * G modulation, in place on S --------------
// attn_qk = w*c/(c*T+eps), w = exp(s-m)*G_qk, G_qk = gw_q . gw_k,
// c = n/(Z*(SG+eps)); Z,SG,T row sums of exp, G, w. Exactly matches reference
// (scores-softmax, G row-normalized *n, product, renormalize) incl. both eps.
__device__ __forceinline__ float blk_reduce(float v, float* red, int tid, bool is_max)
{
    red[tid] = v; __syncthreads();
    for (int off = 128; off; off >>= 1) {
        if (tid < off) red[tid] = is_max ? fmaxf(red[tid], red[tid + off])
                                         : red[tid] + red[tid + off];
        __syncthreads();
    }
    float r = red[0]; __syncthreads();
    return r;
}

__global__ __launch_bounds__(256)
void mod_k(float* __restrict__ S, const float* __restrict__ gw)
{
    const int q = blockIdx.x;            // 0..1023
    const int b = blockIdx.y;            // chunk-local batch
    const int tid = threadIdx.x;
    float* Srow = S + ((long long)b * 1024 + q) * 1024;
    const float* gwb = gw + (long long)b * 1024 * 49;

    __shared__ float gwq[49];
    __shared__ float red[256];
    if (tid < 49) gwq[tid] = gwb[q * 49 + tid];
    __syncthreads();

    float m = -INFINITY;
#pragma unroll
    for (int i = 0; i < 4; ++i) m = fmaxf(m, Srow[tid + 256 * i]);
    m = blk_reduce(m, red, tid, true);

    float Z = 0.f, SG = 0.f, T = 0.f;
    float wloc[4];
#pragma unroll
    for (int i = 0; i < 4; ++i) {
        const int k = tid + 256 * i;
        float e = expf(Srow[k] - m);
        const float* gwk = gwb + k * 49;
        float g = 0.f;
        for (int j = 0; j < 49; ++j) g = fmaf(gwq[j], gwk[j], g);
        float w = e * g;
        wloc[i] = w;
        Z += e; SG += g; T += w;
    }
    Z  = blk_reduce(Z,  red, tid, false);
    SG = blk_reduce(SG, red, tid, false);
    T  = blk_reduce(T,  red, tid, false);

    const float c = 1024.f / (Z * (SG + 1e-8f));
    const float f = c / (c * T + 1e-8f);
#pragma unroll
    for (int i = 0; i < 4; ++i) Srow[tid + 256 * i] = wloc[i] * f;
}

extern "C" void kernel_launch(void* const* d_in, const int* in_sizes, int n_in,
                              void* d_out, int out_size, void* d_ws, size_t ws_size,
                              hipStream_t stream)
{
    const float* x      = (const float*)d_in[0];   // [32,1024,768]
    const float* w_qkv  = (const float*)d_in[1];   // [768,2304]
    const float* b_qkv  = (const float*)d_in[2];   // [2304]
    const float* w_proj = (const float*)d_in[3];   // [768,768]
    const float* b_proj = (const float*)d_in[4];   // [768]
    const float* w_gp   = (const float*)d_in[5];   // [768,49]
    float* out = (float*)d_out;
    float* ws  = (float*)d_ws;

    // Batch-chunked pipeline: CB=4 batches per chunk, scratch reused across
    // chunks (stream-serialized). Scratch layout (floats):
    //   qkvC [4*1024, 2304]  = 9,437,184
    //   SC   [4, 1024, 1024] = 4,194,304
    //   gwC  [4*1024, 49]    =   200,704
    // total 13,832,192 floats = 55.3 MB  (vs 443 MB in R1 -> ws overflow fix)
    const int  CB   = 4;
    const int  MC   = CB * 1024;                   // 4096 rows per chunk
    float* qkvC = ws;
    float* SC   = ws + 9437184LL;
    float* gwC  = ws + 13631488LL;

    const long long sQKV = 1024LL * 2304;          // per-batch stride in qkvC
    const long long sS   = 1024LL * 1024;
    const float scale = 1.0f / sqrtf(768.0f);

    for (int c = 0; c < 32 / CB; ++c) {
        const float* xc   = x   + (long long)c * MC * 768;
        float*       outc = out + (long long)c * MC * 768;

        // 1) qkvC = xc @ w_qkv + b_qkv   [4096 x 2304], K=768
        gemm_k<false, true><<<dim3(36, MC / 64, 1), 256, 0, stream>>>(
            xc, w_qkv, b_qkv, qkvC, 768, 768, 2304, 2304, 0, 0, 0, 1.0f);

        // 2) gwC = softmax(V @ w_gp)
        gw_k<<<dim3(MC), 64, 0, stream>>>(qkvC, w_gp, gwC);

        // 3) SC = Q @ K^T * scale   per batch [1024 x 1024], K=768
        gemm_k<true, false><<<dim3(16, 16, CB), 256, 0, stream>>>(
            qkvC, qkvC + 768, nullptr, SC, 768, 2304, 2304, 1024, sQKV, sQKV, sS, scale);

        // 4) attn = normalize(softmax(SC) * G) in place
        mod_k<<<dim3(1024, CB), 256, 0, stream>>>(SC, gwC);

        // 5) O = attn @ V  -> aliased onto Q columns of qkvC (Q dead now)
        gemm_k<false, false><<<dim3(12, 16, CB), 256, 0, stream>>>(
            SC, qkvC + 1536, nullptr, qkvC, 1024, 1024, 2304, 2304, sS, sQKV, sQKV, 1.0f);

        // 6) outc = O @ w_proj + b_proj   [4096 x 768], K=768
        gemm_k<false, true><<<dim3(12, MC / 64, 1), 256, 0, stream>>>(
            qkvC, w_proj, b_proj, outc, 768, 2304, 768, 768, 0, 0, 0, 1.0f);
    }
}